// Round 2
// baseline (677.976 us; speedup 1.0000x reference)
//
#include <hip/hip_runtime.h>
#include <cstddef>

// MediumLSTM v2: 3 layer-split kernels, weights in VGPRs, x/h1/h2 A-frags
// straight from global (prefetched), double-buffered h-state LDS -> ONE
// barrier per timestep. Inter-layer hidden states round-trip through d_ws
// as f16 in [block][t][row16][unit] layout == consumer's MFMA-A fragment
// layout (b128 coalesced loads, zero reformat).
//
// Gate permutation (same as v1, verified): wave's N-tile columns hold
// complete i/f/g/o for its hidden units; state update via intra-quad __shfl.

typedef _Float16 h8_t  __attribute__((ext_vector_type(8)));
typedef float    f4_t  __attribute__((ext_vector_type(4)));

#define B_TOT 8192
#define T_LEN 64
#define D_IN  128
#define MB    16          // batch rows per block
#define NBLK  (B_TOT/MB)  // 512

#define H1G_ELEMS ((size_t)NBLK * T_LEN * 16 * 32)   // 16,777,216 f16 = 33.55 MB
#define H2G_ELEMS ((size_t)NBLK * T_LEN * 16 * 16)   //  8,388,608 f16 = 16.78 MB

__device__ __forceinline__ float sig_(float x)  { return 1.0f / (1.0f + __expf(-x)); }
__device__ __forceinline__ float tanh_(float x) { float e = __expf(2.0f * x); return 1.0f - 2.0f / (e + 1.0f); }

__device__ __forceinline__ h8_t load8f_h(const float* __restrict__ p) {
    f4_t lo = *(const f4_t*)p, hi = *(const f4_t*)(p + 4);
    h8_t r = { (_Float16)lo[0], (_Float16)lo[1], (_Float16)lo[2], (_Float16)lo[3],
               (_Float16)hi[0], (_Float16)hi[1], (_Float16)hi[2], (_Float16)hi[3] };
    return r;
}
__device__ __forceinline__ h8_t zero8h() {
    h8_t r = { (_Float16)0.f,(_Float16)0.f,(_Float16)0.f,(_Float16)0.f,
               (_Float16)0.f,(_Float16)0.f,(_Float16)0.f,(_Float16)0.f };
    return r;
}

// ---------------- Layer 1: x[B,T,128] -> h1g [blk][t][16][32] f16 ----------------
__global__ __launch_bounds__(256, 2)
void k_l1(const float* __restrict__ x,
          const float* __restrict__ w_ih1, const float* __restrict__ w_hh1,
          const float* __restrict__ b_ih1, const float* __restrict__ b_hh1,
          _Float16* __restrict__ h1g)
{
    __shared__ _Float16 h1buf[2][16][40];   // dbuf; stride 40 f16 (20 words)

    const int tid = threadIdx.x, lane = tid & 63, wv = tid >> 6;
    const int nl = lane & 15, qd = lane >> 4;
    const int sh8 = (lane & 48) | ((lane + 8) & 15);

    // ---- B-fragments in VGPRs (invariant over t) ----
    // tile tau cols s=16*tau+nl -> original gate row G = 8wv + (s&7) + 32*(s>>3)
    h8_t bw[2][4];   // [tau][kc] w_ih1 frags (K=128)
    h8_t bh[2];      // [tau]     w_hh1 frags (K=32)
    float bias[4];
    {
        #pragma unroll
        for (int tau = 0; tau < 2; ++tau) {
            int s = 16 * tau + nl;
            int G = 8 * wv + (s & 7) + 32 * (s >> 3);
            #pragma unroll
            for (int kc = 0; kc < 4; ++kc)
                bw[tau][kc] = load8f_h(w_ih1 + G * 128 + kc * 32 + qd * 8);
            bh[tau] = load8f_h(w_hh1 + G * 32 + qd * 8);
        }
        int u = 8 * wv + (nl & 7);
        bias[0] = b_ih1[u]      + b_hh1[u];
        bias[1] = b_ih1[u + 32] + b_hh1[u + 32];
        bias[2] = b_ih1[u + 64] + b_hh1[u + 64];
        bias[3] = b_ih1[u + 96] + b_hh1[u + 96];
    }

    for (int i = tid; i < 2 * 16 * 40; i += 256) ((_Float16*)h1buf)[i] = (_Float16)0.f;
    float c1[4] = {0.f, 0.f, 0.f, 0.f};
    __syncthreads();

    // x A-frag: lane (nl,qd) covers row (b0+nl), k = kc*32 + qd*8 + j
    const float* xrow = x + ((size_t)(blockIdx.x * MB + nl) * T_LEN) * D_IN + qd * 8;
    f4_t xa[8];
    #pragma unroll
    for (int kc = 0; kc < 4; ++kc) {
        xa[2 * kc]     = *(const f4_t*)(xrow + kc * 32);
        xa[2 * kc + 1] = *(const f4_t*)(xrow + kc * 32 + 4);
    }

    int p = 0;
    for (int t = 0; t < T_LEN; ++t) {
        // convert current x to f16 frags, then prefetch t+1 (overwrites xa)
        h8_t af[4];
        #pragma unroll
        for (int kc = 0; kc < 4; ++kc) {
            f4_t lo = xa[2 * kc], hi = xa[2 * kc + 1];
            h8_t a = { (_Float16)lo[0], (_Float16)lo[1], (_Float16)lo[2], (_Float16)lo[3],
                       (_Float16)hi[0], (_Float16)hi[1], (_Float16)hi[2], (_Float16)hi[3] };
            af[kc] = a;
        }
        if (t + 1 < T_LEN) {
            const float* xn = xrow + (size_t)(t + 1) * D_IN;
            #pragma unroll
            for (int kc = 0; kc < 4; ++kc) {
                xa[2 * kc]     = *(const f4_t*)(xn + kc * 32);
                xa[2 * kc + 1] = *(const f4_t*)(xn + kc * 32 + 4);
            }
        }

        h8_t ah = *(const h8_t*)(&h1buf[p][nl][qd * 8]);   // prev h1 A-frag

        f4_t acc0 = {0.f, 0.f, 0.f, 0.f}, acc1 = {0.f, 0.f, 0.f, 0.f};
        #pragma unroll
        for (int kc = 0; kc < 4; ++kc) {
            acc0 = __builtin_amdgcn_mfma_f32_16x16x32_f16(af[kc], bw[0][kc], acc0, 0, 0, 0);
            acc1 = __builtin_amdgcn_mfma_f32_16x16x32_f16(af[kc], bw[1][kc], acc1, 0, 0, 0);
        }
        acc0 = __builtin_amdgcn_mfma_f32_16x16x32_f16(ah, bh[0], acc0, 0, 0, 0);
        acc1 = __builtin_amdgcn_mfma_f32_16x16x32_f16(ah, bh[1], acc1, 0, 0, 0);

        _Float16* h1o = h1g + (((size_t)blockIdx.x * T_LEN + t) * 16) * 32;
        #pragma unroll
        for (int r = 0; r < 4; ++r) {
            float fsh = __shfl(acc0[r], sh8, 64);
            float osh = __shfl(acc1[r], sh8, 64);
            if (nl < 8) {
                int u = 8 * wv + nl, m = 4 * qd + r;
                float pi = acc0[r] + bias[0];
                float pf = fsh     + bias[1];
                float pg = acc1[r] + bias[2];
                float po = osh     + bias[3];
                float ig = sig_(pi), fg = sig_(pf), gg = tanh_(pg), og = sig_(po);
                float c = fg * c1[r] + ig * gg; c1[r] = c;
                float h = og * tanh_(c);
                h1buf[1 - p][m][u] = (_Float16)h;
                h1o[m * 32 + u]    = (_Float16)h;
            }
        }
        __syncthreads();   // the ONE barrier: buf[1-p] visible; buf[p] safe to rewrite
        p ^= 1;
    }
}

// ---------------- Layer 2: h1g -> h2g [blk][t][16][16] f16 ----------------
__global__ __launch_bounds__(256, 2)
void k_l2(const _Float16* __restrict__ h1g,
          const float* __restrict__ w_ih2, const float* __restrict__ w_hh2,
          const float* __restrict__ b_ih2, const float* __restrict__ b_hh2,
          _Float16* __restrict__ h2g)
{
    __shared__ _Float16 h2buf[2][16][20];

    const int tid = threadIdx.x, lane = tid & 63, wv = tid >> 6;
    const int nl = lane & 15, qd = lane >> 4;
    const int sh4  = (lane & 48) | ((lane + 4)  & 15);
    const int sh8  = (lane & 48) | ((lane + 8)  & 15);
    const int sh12 = (lane & 48) | ((lane + 12) & 15);

    // wave wv owns units [4wv,4wv+4); col s=nl -> G2 = 4wv + (s&3) + 16*(s>>2)
    h8_t bw, bh = zero8h();
    float bias[4];
    {
        int G = 4 * wv + (nl & 3) + 16 * (nl >> 2);
        bw = load8f_h(w_ih2 + G * 32 + qd * 8);          // proj K=32 exact
        if (qd < 2) bh = load8f_h(w_hh2 + G * 16 + qd * 8);  // rec K=16, rest 0
        int u = 4 * wv + (nl & 3);
        bias[0] = b_ih2[u]      + b_hh2[u];
        bias[1] = b_ih2[u + 16] + b_hh2[u + 16];
        bias[2] = b_ih2[u + 32] + b_hh2[u + 32];
        bias[3] = b_ih2[u + 48] + b_hh2[u + 48];
    }

    for (int i = tid; i < 2 * 16 * 20; i += 256) ((_Float16*)h2buf)[i] = (_Float16)0.f;
    float c2[4] = {0.f, 0.f, 0.f, 0.f};
    __syncthreads();

    const _Float16* h1base = h1g + ((size_t)blockIdx.x * T_LEN) * 16 * 32 + nl * 32 + qd * 8;
    h8_t a_cur = *(const h8_t*)(h1base);   // t=0, b128 coalesced
    int p = 0;
    for (int t = 0; t < T_LEN; ++t) {
        h8_t a_nxt = zero8h();
        if (t + 1 < T_LEN) a_nxt = *(const h8_t*)(h1base + (size_t)(t + 1) * 16 * 32);

        h8_t ah = zero8h();
        if (qd < 2) ah = *(const h8_t*)(&h2buf[p][nl][qd * 8]);

        f4_t acc = {0.f, 0.f, 0.f, 0.f};
        acc = __builtin_amdgcn_mfma_f32_16x16x32_f16(a_cur, bw, acc, 0, 0, 0);
        acc = __builtin_amdgcn_mfma_f32_16x16x32_f16(ah,    bh, acc, 0, 0, 0);

        _Float16* h2o = h2g + (((size_t)blockIdx.x * T_LEN + t) * 16) * 16;
        #pragma unroll
        for (int r = 0; r < 4; ++r) {
            float fsh = __shfl(acc[r], sh4, 64);
            float gsh = __shfl(acc[r], sh8, 64);
            float osh = __shfl(acc[r], sh12, 64);
            if (nl < 4) {
                int u = 4 * wv + nl, m = 4 * qd + r;
                float pi = acc[r] + bias[0];
                float pf = fsh    + bias[1];
                float pg = gsh    + bias[2];
                float po = osh    + bias[3];
                float ig = sig_(pi), fg = sig_(pf), gg = tanh_(pg), og = sig_(po);
                float c = fg * c2[r] + ig * gg; c2[r] = c;
                float h = og * tanh_(c);
                h2buf[1 - p][m][u] = (_Float16)h;
                h2o[m * 16 + u]    = (_Float16)h;
            }
        }
        __syncthreads();
        p ^= 1; a_cur = a_nxt;
    }
}

// ---------------- Layer 3 + FC: h2g -> out[8192] ----------------
__global__ __launch_bounds__(256, 2)
void k_l3(const _Float16* __restrict__ h2g,
          const float* __restrict__ w_ih3, const float* __restrict__ w_hh3,
          const float* __restrict__ b_ih3, const float* __restrict__ b_hh3,
          const float* __restrict__ fc_w, const float* __restrict__ fc_b,
          float* __restrict__ out)
{
    __shared__ _Float16 h3buf[2][16][12];
    __shared__ _Float16 h3fin[16][8];

    const int tid = threadIdx.x, lane = tid & 63, wv = tid >> 6;
    const int nl = lane & 15, qd = lane >> 4;
    const int sh4  = (lane & 48) | ((lane + 4)  & 15);
    const int sh8  = (lane & 48) | ((lane + 8)  & 15);
    const int sh12 = (lane & 48) | ((lane + 12) & 15);

    // waves 0,1 own units [4wv,4wv+4); combined B-frag: k=qd*8+j:
    //   qd0,1 -> w_ih3[G][k] (K=16 proj from h2_t), qd2 -> w_hh3[G][j] (rec h3), qd3 -> 0
    h8_t bc = zero8h();
    float bias[4] = {0.f, 0.f, 0.f, 0.f};
    if (wv < 2) {
        int G = 4 * wv + (nl & 3) + 8 * (nl >> 2);
        if (qd < 2)       bc = load8f_h(w_ih3 + G * 16 + qd * 8);
        else if (qd == 2) bc = load8f_h(w_hh3 + G * 8);
        int u = 4 * wv + (nl & 3);
        bias[0] = b_ih3[u]      + b_hh3[u];
        bias[1] = b_ih3[u + 8]  + b_hh3[u + 8];
        bias[2] = b_ih3[u + 16] + b_hh3[u + 16];
        bias[3] = b_ih3[u + 24] + b_hh3[u + 24];
    }

    for (int i = tid; i < 2 * 16 * 12; i += 256) ((_Float16*)h3buf)[i] = (_Float16)0.f;
    float c3[4] = {0.f, 0.f, 0.f, 0.f};
    __syncthreads();

    const _Float16* h2base = h2g + ((size_t)blockIdx.x * T_LEN) * 16 * 16 + nl * 16 + qd * 8;
    h8_t a_cur = zero8h();
    if (wv < 2 && qd < 2) a_cur = *(const h8_t*)(h2base);
    int p = 0;
    for (int t = 0; t < T_LEN; ++t) {
        h8_t a_nxt = zero8h();
        if (wv < 2 && qd < 2 && t + 1 < T_LEN)
            a_nxt = *(const h8_t*)(h2base + (size_t)(t + 1) * 16 * 16);

        if (wv < 2) {
            h8_t af = a_cur;                                   // qd0,1: h2_t ; qd3: 0
            if (qd == 2) af = *(const h8_t*)(&h3buf[p][nl][0]); // qd2: prev h3
            f4_t acc = {0.f, 0.f, 0.f, 0.f};
            acc = __builtin_amdgcn_mfma_f32_16x16x32_f16(af, bc, acc, 0, 0, 0);
            #pragma unroll
            for (int r = 0; r < 4; ++r) {
                float fsh = __shfl(acc[r], sh4, 64);
                float gsh = __shfl(acc[r], sh8, 64);
                float osh = __shfl(acc[r], sh12, 64);
                if (nl < 4) {
                    int u = 4 * wv + nl, m = 4 * qd + r;
                    float pi = acc[r] + bias[0];
                    float pf = fsh    + bias[1];
                    float pg = gsh    + bias[2];
                    float po = osh    + bias[3];
                    float ig = sig_(pi), fg = sig_(pf), gg = tanh_(pg), og = sig_(po);
                    float c = fg * c3[r] + ig * gg; c3[r] = c;
                    float h = og * tanh_(c);
                    h3buf[1 - p][m][u] = (_Float16)h;
                    if (t == T_LEN - 1) h3fin[m][u] = (_Float16)h;
                }
            }
        }
        __syncthreads();
        p ^= 1; a_cur = a_nxt;
    }

    if (tid < MB) {
        float acc = fc_b[0];
        #pragma unroll
        for (int u = 0; u < 8; ++u)
            acc += fc_w[u] * (float)h3fin[tid][u];
        out[blockIdx.x * MB + tid] = acc;
    }
}

extern "C" void kernel_launch(void* const* d_in, const int* in_sizes, int n_in,
                              void* d_out, int out_size, void* d_ws, size_t ws_size,
                              hipStream_t stream) {
    (void)in_sizes; (void)n_in; (void)out_size; (void)ws_size;
    const float* x     = (const float*)d_in[0];
    const float* w_ih1 = (const float*)d_in[1];
    const float* w_hh1 = (const float*)d_in[2];
    const float* b_ih1 = (const float*)d_in[3];
    const float* b_hh1 = (const float*)d_in[4];
    const float* w_ih2 = (const float*)d_in[5];
    const float* w_hh2 = (const float*)d_in[6];
    const float* b_ih2 = (const float*)d_in[7];
    const float* b_hh2 = (const float*)d_in[8];
    const float* w_ih3 = (const float*)d_in[9];
    const float* w_hh3 = (const float*)d_in[10];
    const float* b_ih3 = (const float*)d_in[11];
    const float* b_hh3 = (const float*)d_in[12];
    const float* fc_w  = (const float*)d_in[13];
    const float* fc_b  = (const float*)d_in[14];

    _Float16* h1g = (_Float16*)d_ws;                 // 33.55 MB
    _Float16* h2g = (_Float16*)d_ws + H1G_ELEMS;     // +16.78 MB = 50.33 MB total

    dim3 grid(NBLK), block(256);
    hipLaunchKernelGGL(k_l1, grid, block, 0, stream,
                       x, w_ih1, w_hh1, b_ih1, b_hh1, h1g);
    hipLaunchKernelGGL(k_l2, grid, block, 0, stream,
                       h1g, w_ih2, w_hh2, b_ih2, b_hh2, h2g);
    hipLaunchKernelGGL(k_l3, grid, block, 0, stream,
                       h2g, w_ih3, w_hh3, b_ih3, b_hh3, fc_w, fc_b, (float*)d_out);
}

// Round 4
// 544.966 us; speedup vs baseline: 1.2441x; 1.2441x over previous
//
#include <hip/hip_runtime.h>
#include <cstddef>

// MediumLSTM v3.1: ONE fused kernel, one wave per 16 batch rows, ZERO barriers.
// 512 blocks x 64 threads. All weights live in VGPRs (gate-permuted B-frags).
// Recurrence is wave-local: h-state round-trips through a tiny private LDS
// region (in-wave ds ordering, lgkmcnt only -- no s_barrier, so no vmcnt(0)
// drain on the critical path). Gate extraction from MFMA C-layout uses
// __shfl_xor(.,8) with a duo permutation that keeps ALL 64 lanes doing
// epilogue work.
//
// v3.1 fix: __builtin_amdgcn_cvt_pkrtz returns __fp16x2, not _Float16x2 --
// union uses __fp16-typed pairs (bit-identical reinterpret, same codegen).
//
// Gate permutation per layer: even tiles hold (i | f) gate columns, odd tiles
// hold (g | o), unit halves split across the 16 columns so:
//   lane nl<8  owns unit (lo-half): i/g in own column, f/o at column^8
//   lane nl>=8 owns unit (hi-half): f/o in own column, i/g at column^8
// -> 4 shfl_xor + 4 cndmask per unit-row group, no idle lanes.

typedef _Float16 h8_t  __attribute__((ext_vector_type(8)));
typedef __fp16   p2_t  __attribute__((ext_vector_type(2)));
typedef float    f4_t  __attribute__((ext_vector_type(4)));

#define T_LEN 64
#define D_IN  128

__device__ __forceinline__ float sig_(float x)  { return 1.0f / (1.0f + __expf(-x)); }
__device__ __forceinline__ float tanh_(float x) { float e = __expf(2.0f * x); return 1.0f - 2.0f / (e + 1.0f); }

__device__ __forceinline__ h8_t zero8h() {
    h8_t r = { (_Float16)0.f,(_Float16)0.f,(_Float16)0.f,(_Float16)0.f,
               (_Float16)0.f,(_Float16)0.f,(_Float16)0.f,(_Float16)0.f };
    return r;
}
__device__ __forceinline__ h8_t cvt8(f4_t lo, f4_t hi) {
    union { h8_t v8; p2_t v2[4]; } u;
    u.v2[0] = __builtin_amdgcn_cvt_pkrtz(lo[0], lo[1]);
    u.v2[1] = __builtin_amdgcn_cvt_pkrtz(lo[2], lo[3]);
    u.v2[2] = __builtin_amdgcn_cvt_pkrtz(hi[0], hi[1]);
    u.v2[3] = __builtin_amdgcn_cvt_pkrtz(hi[2], hi[3]);
    return u.v8;
}
__device__ __forceinline__ h8_t load8f_h(const float* __restrict__ p) {
    f4_t lo = *(const f4_t*)p, hi = *(const f4_t*)(p + 4);
    return cvt8(lo, hi);
}

__global__ __launch_bounds__(64, 1)
void lstm_one(const float* __restrict__ x,
              const float* __restrict__ w_ih1, const float* __restrict__ w_hh1,
              const float* __restrict__ b_ih1, const float* __restrict__ b_hh1,
              const float* __restrict__ w_ih2, const float* __restrict__ w_hh2,
              const float* __restrict__ b_ih2, const float* __restrict__ b_hh2,
              const float* __restrict__ w_ih3, const float* __restrict__ w_hh3,
              const float* __restrict__ b_ih3, const float* __restrict__ b_hh3,
              const float* __restrict__ fc_w, const float* __restrict__ fc_b,
              float* __restrict__ out)
{
    // single wave per block: single-buffered, wave-synchronous LDS
    __shared__ _Float16 h1s[16][40];   // stride 40 hw = 80 B (16B aligned rows)
    __shared__ _Float16 h2s[16][24];
    __shared__ _Float16 h3s[16][8];

    const int lane = threadIdx.x;      // 0..63
    const int nl = lane & 15, qd = lane >> 4;
    const bool lo8 = (nl & 8) == 0;

    // ---------------- stage weights into VGPRs (gate-permuted) ----------------
    // L1: tile tau=2w+j (w=0..3, j=0..1), col s=nl:
    //     G = 8w + (s&7) + 32*((s>>3) + 2j)   -> tile 2w = (i|f), 2w+1 = (g|o)
    h8_t bw1[8][4], bh1[8];
    #pragma unroll
    for (int tau = 0; tau < 8; ++tau) {
        int w = tau >> 1, j = tau & 1;
        int G = 8 * w + (nl & 7) + 32 * ((nl >> 3) + 2 * j);
        #pragma unroll
        for (int kc = 0; kc < 4; ++kc)
            bw1[tau][kc] = load8f_h(w_ih1 + G * 128 + kc * 32 + qd * 8);
        bh1[tau] = load8f_h(w_hh1 + G * 32 + qd * 8);
    }
    // L2: tile tau=2a+b (a=unit half, b=gate pair): G = 32b + 16*(s>>3) + 8a + (s&7)
    h8_t bw2[4], bh2[4];
    #pragma unroll
    for (int tau = 0; tau < 4; ++tau) {
        int a = tau >> 1, b = tau & 1;
        int G = 32 * b + 16 * (nl >> 3) + 8 * a + (nl & 7);
        bw2[tau] = load8f_h(w_ih2 + G * 32 + qd * 8);
        bh2[tau] = (qd < 2) ? load8f_h(w_hh2 + G * 16 + qd * 8) : zero8h();
    }
    // L3: tile tau=b: G = 16b + 8*(s>>3) + (s&7). Combined K: qd0,1=w_ih3(K16),
    // qd2=w_hh3(K8), qd3=0  (A side supplies h2|h3|0 to match)
    h8_t b3c[2];
    #pragma unroll
    for (int tau = 0; tau < 2; ++tau) {
        int G = 16 * tau + 8 * (nl >> 3) + (nl & 7);
        b3c[tau] = (qd < 2) ? load8f_h(w_ih3 + G * 16 + qd * 8)
                 : (qd == 2) ? load8f_h(w_hh3 + G * 8) : zero8h();
    }
    // per-lane biases for owned units
    float bs1[2][4], bs2[4], bs3[4];
    #pragma unroll
    for (int d = 0; d < 2; ++d) {
        int U = 16 * d + nl;
        #pragma unroll
        for (int g = 0; g < 4; ++g) bs1[d][g] = b_ih1[32 * g + U] + b_hh1[32 * g + U];
    }
    #pragma unroll
    for (int g = 0; g < 4; ++g) bs2[g] = b_ih2[16 * g + nl] + b_hh2[16 * g + nl];
    {
        int u3 = nl & 7;
        #pragma unroll
        for (int g = 0; g < 4; ++g) bs3[g] = b_ih3[8 * g + u3] + b_hh3[8 * g + u3];
    }

    // zero h-state LDS (same wave writes & reads -> no barrier needed)
    for (int i = lane; i < 16 * 40; i += 64) (&h1s[0][0])[i] = (_Float16)0.f;
    for (int i = lane; i < 16 * 24; i += 64) (&h2s[0][0])[i] = (_Float16)0.f;
    for (int i = lane; i < 16 * 8;  i += 64) (&h3s[0][0])[i] = (_Float16)0.f;

    float c1[2][4] = {{0.f,0.f,0.f,0.f},{0.f,0.f,0.f,0.f}};
    float c2v[4] = {0.f,0.f,0.f,0.f};
    float c3v[2] = {0.f,0.f};

    const int b0 = blockIdx.x * 16;
    const float* xbase = x + ((size_t)(b0 + nl) * T_LEN) * D_IN + qd * 8;
    f4_t xa[8];
    #pragma unroll
    for (int kc = 0; kc < 4; ++kc) {
        xa[2 * kc]     = *(const f4_t*)(xbase + kc * 32);
        xa[2 * kc + 1] = *(const f4_t*)(xbase + kc * 32 + 4);
    }

    for (int t = 0; t < T_LEN; ++t) {
        // convert x_t, then prefetch x_{t+1} (no barrier -> no forced drain)
        h8_t af[4];
        #pragma unroll
        for (int kc = 0; kc < 4; ++kc) af[kc] = cvt8(xa[2 * kc], xa[2 * kc + 1]);
        if (t + 1 < T_LEN) {
            const float* xn = xbase + (size_t)(t + 1) * D_IN;
            #pragma unroll
            for (int kc = 0; kc < 4; ++kc) {
                xa[2 * kc]     = *(const f4_t*)(xn + kc * 32);
                xa[2 * kc + 1] = *(const f4_t*)(xn + kc * 32 + 4);
            }
        }

        // ---------------- Layer 1: 32 units, 8 tiles, K=128(+32 rec) ----------------
        h8_t a1p = *(const h8_t*)&h1s[nl][qd * 8];    // h1[t-1]
        f4_t acc[8];
        #pragma unroll
        for (int tau = 0; tau < 8; ++tau) {
            f4_t a_ = {0.f, 0.f, 0.f, 0.f};
            #pragma unroll
            for (int kc = 0; kc < 4; ++kc)
                a_ = __builtin_amdgcn_mfma_f32_16x16x32_f16(af[kc], bw1[tau][kc], a_, 0, 0, 0);
            a_ = __builtin_amdgcn_mfma_f32_16x16x32_f16(a1p, bh1[tau], a_, 0, 0, 0);
            acc[tau] = a_;
        }
        #pragma unroll
        for (int d = 0; d < 2; ++d)
        #pragma unroll
        for (int r = 0; r < 4; ++r) {
            float eL = acc[4*d+0][r], oL = acc[4*d+1][r];
            float eH = acc[4*d+2][r], oH = acc[4*d+3][r];
            float exL = __shfl_xor(eL, 8, 64), exH = __shfl_xor(eH, 8, 64);
            float oxL = __shfl_xor(oL, 8, 64), oxH = __shfl_xor(oH, 8, 64);
            float vi = lo8 ? eL  : exH;
            float vf = lo8 ? exL : eH;
            float vg = lo8 ? oL  : oxH;
            float vo = lo8 ? oxL : oH;
            float ig = sig_(vi + bs1[d][0]);
            float fg = sig_(vf + bs1[d][1]);
            float gg = tanh_(vg + bs1[d][2]);
            float og = sig_(vo + bs1[d][3]);
            float c = fg * c1[d][r] + ig * gg; c1[d][r] = c;
            float h = og * tanh_(c);
            h1s[4 * qd + r][16 * d + nl] = (_Float16)h;   // h1[t]
        }

        // ---------------- Layer 2: 16 units, 4 tiles, K=32(+16 rec) ----------------
        h8_t a1c = *(const h8_t*)&h1s[nl][qd * 8];    // h1[t] (in-wave ordered)
        h8_t a2p = zero8h();
        if (qd < 2) a2p = *(const h8_t*)&h2s[nl][qd * 8];   // h2[t-1]
        f4_t acc2[4];
        #pragma unroll
        for (int tau = 0; tau < 4; ++tau) {
            f4_t a_ = {0.f, 0.f, 0.f, 0.f};
            a_ = __builtin_amdgcn_mfma_f32_16x16x32_f16(a1c, bw2[tau], a_, 0, 0, 0);
            a_ = __builtin_amdgcn_mfma_f32_16x16x32_f16(a2p, bh2[tau], a_, 0, 0, 0);
            acc2[tau] = a_;
        }
        #pragma unroll
        for (int r = 0; r < 4; ++r) {
            float eL = acc2[0][r], oL = acc2[1][r];
            float eH = acc2[2][r], oH = acc2[3][r];
            float exL = __shfl_xor(eL, 8, 64), exH = __shfl_xor(eH, 8, 64);
            float oxL = __shfl_xor(oL, 8, 64), oxH = __shfl_xor(oH, 8, 64);
            float vi = lo8 ? eL  : exH;
            float vf = lo8 ? exL : eH;
            float vg = lo8 ? oL  : oxH;
            float vo = lo8 ? oxL : oH;
            float ig = sig_(vi + bs2[0]);
            float fg = sig_(vf + bs2[1]);
            float gg = tanh_(vg + bs2[2]);
            float og = sig_(vo + bs2[3]);
            float c = fg * c2v[r] + ig * gg; c2v[r] = c;
            float h = og * tanh_(c);
            h2s[4 * qd + r][nl] = (_Float16)h;            // h2[t]
        }

        // ---------------- Layer 3: 8 units, 2 tiles, combined K=32 ----------------
        h8_t a3 = zero8h();
        if (qd < 2)       a3 = *(const h8_t*)&h2s[nl][qd * 8];  // h2[t]
        else if (qd == 2) a3 = *(const h8_t*)&h3s[nl][0];       // h3[t-1]
        f4_t acc3[2];
        #pragma unroll
        for (int tau = 0; tau < 2; ++tau) {
            f4_t a_ = {0.f, 0.f, 0.f, 0.f};
            acc3[tau] = __builtin_amdgcn_mfma_f32_16x16x32_f16(a3, b3c[tau], a_, 0, 0, 0);
        }
        #pragma unroll
        for (int rp = 0; rp < 2; ++rp) {
            float eLo = acc3[0][rp],     oLo = acc3[1][rp];
            float eHi = acc3[0][rp + 2], oHi = acc3[1][rp + 2];
            float exLo = __shfl_xor(eLo, 8, 64), exHi = __shfl_xor(eHi, 8, 64);
            float oxLo = __shfl_xor(oLo, 8, 64), oxHi = __shfl_xor(oHi, 8, 64);
            float vi = lo8 ? eLo  : exHi;
            float vf = lo8 ? exLo : eHi;
            float vg = lo8 ? oLo  : oxHi;
            float vo = lo8 ? oxLo : oHi;
            float ig = sig_(vi + bs3[0]);
            float fg = sig_(vf + bs3[1]);
            float gg = tanh_(vg + bs3[2]);
            float og = sig_(vo + bs3[3]);
            float c = fg * c3v[rp] + ig * gg; c3v[rp] = c;
            float h = og * tanh_(c);
            int m = 4 * qd + rp + (lo8 ? 0 : 2);          // lanes<8: rows r0,1; >=8: r2,3
            h3s[m][nl & 7] = (_Float16)h;                 // h3[t]
        }
    }

    // ---------------- FC head ----------------
    if (lane < 16) {
        float a = fc_b[0];
        #pragma unroll
        for (int u = 0; u < 8; ++u)
            a += fc_w[u] * (float)h3s[lane][u];
        out[b0 + lane] = a;
    }
}

extern "C" void kernel_launch(void* const* d_in, const int* in_sizes, int n_in,
                              void* d_out, int out_size, void* d_ws, size_t ws_size,
                              hipStream_t stream) {
    (void)in_sizes; (void)n_in; (void)out_size; (void)d_ws; (void)ws_size;
    const float* x     = (const float*)d_in[0];
    const float* w_ih1 = (const float*)d_in[1];
    const float* w_hh1 = (const float*)d_in[2];
    const float* b_ih1 = (const float*)d_in[3];
    const float* b_hh1 = (const float*)d_in[4];
    const float* w_ih2 = (const float*)d_in[5];
    const float* w_hh2 = (const float*)d_in[6];
    const float* b_ih2 = (const float*)d_in[7];
    const float* b_hh2 = (const float*)d_in[8];
    const float* w_ih3 = (const float*)d_in[9];
    const float* w_hh3 = (const float*)d_in[10];
    const float* b_ih3 = (const float*)d_in[11];
    const float* b_hh3 = (const float*)d_in[12];
    const float* fc_w  = (const float*)d_in[13];
    const float* fc_b  = (const float*)d_in[14];

    dim3 grid(512), block(64);
    hipLaunchKernelGGL(lstm_one, grid, block, 0, stream,
                       x, w_ih1, w_hh1, b_ih1, b_hh1,
                       w_ih2, w_hh2, b_ih2, b_hh2,
                       w_ih3, w_hh3, b_ih3, b_hh3,
                       fc_w, fc_b, (float*)d_out);
}

// Round 5
// 530.264 us; speedup vs baseline: 1.2786x; 1.0277x over previous
//
#include <hip/hip_runtime.h>
#include <cstddef>
#include <type_traits>

// MediumLSTM v4: layer-delay software pipeline, zero barriers, one wave / 16 rows.
// At iteration t: L1 -> h1[t], L2 -> h2[t-1], L3 -> h3[t-2]. The three chains are
// mutually independent within an iteration, so the compiler interleaves them into
// each other's stall slots (v3.1 was one serial chain = 10.3k cyc/step, 70% stall).
// h-states double-buffered in LDS with COMPILE-TIME parity (t-loop unrolled x2,
// parity is a template constant) so LLVM can disambiguate and reorder LDS ops.
// Runs T+2 iterations; warm-up/drain phases via constexpr active-layer flags.
//
// Parity map (P = t&1):
//   L1: reads h1s[1-P] (h1[t-1]),  writes h1s[P]   (h1[t])
//   L2: reads h1s[1-P], h2s[P] (h2[t-2]), writes h2s[1-P] (h2[t-1])
//   L3: reads h2s[P] (h2[t-2]), h3s[1-P] (h3[t-3]), writes h3s[P] (h3[t-2])
//   FC: h3[63] lands in h3s[1] (produced at iter 65).

typedef _Float16 h8_t  __attribute__((ext_vector_type(8)));
typedef __fp16   p2_t  __attribute__((ext_vector_type(2)));
typedef float    f4_t  __attribute__((ext_vector_type(4)));

#define T_LEN 64
#define D_IN  128

__device__ __forceinline__ float sig_(float x)  { return 1.0f / (1.0f + __expf(-x)); }
__device__ __forceinline__ float tanh_(float x) { float e = __expf(2.0f * x); return 1.0f - 2.0f / (e + 1.0f); }

__device__ __forceinline__ h8_t zero8h() {
    h8_t r = { (_Float16)0.f,(_Float16)0.f,(_Float16)0.f,(_Float16)0.f,
               (_Float16)0.f,(_Float16)0.f,(_Float16)0.f,(_Float16)0.f };
    return r;
}
__device__ __forceinline__ h8_t cvt8(f4_t lo, f4_t hi) {
    union { h8_t v8; p2_t v2[4]; } u;
    u.v2[0] = __builtin_amdgcn_cvt_pkrtz(lo[0], lo[1]);
    u.v2[1] = __builtin_amdgcn_cvt_pkrtz(lo[2], lo[3]);
    u.v2[2] = __builtin_amdgcn_cvt_pkrtz(hi[0], hi[1]);
    u.v2[3] = __builtin_amdgcn_cvt_pkrtz(hi[2], hi[3]);
    return u.v8;
}
__device__ __forceinline__ h8_t load8f_h(const float* __restrict__ p) {
    f4_t lo = *(const f4_t*)p, hi = *(const f4_t*)(p + 4);
    return cvt8(lo, hi);
}

__global__ __launch_bounds__(64, 1)
void lstm_one(const float* __restrict__ x,
              const float* __restrict__ w_ih1, const float* __restrict__ w_hh1,
              const float* __restrict__ b_ih1, const float* __restrict__ b_hh1,
              const float* __restrict__ w_ih2, const float* __restrict__ w_hh2,
              const float* __restrict__ b_ih2, const float* __restrict__ b_hh2,
              const float* __restrict__ w_ih3, const float* __restrict__ w_hh3,
              const float* __restrict__ b_ih3, const float* __restrict__ b_hh3,
              const float* __restrict__ fc_w, const float* __restrict__ fc_b,
              float* __restrict__ out)
{
    __shared__ _Float16 h1s[2][16][40];
    __shared__ _Float16 h2s[2][16][24];
    __shared__ _Float16 h3s[2][16][8];

    const int lane = threadIdx.x;      // 0..63
    const int nl = lane & 15, qd = lane >> 4;
    const bool lo8 = (nl & 8) == 0;

    // ---------------- weights into VGPRs (gate-permuted, same as v3.1) ----------------
    h8_t bw1[8][4], bh1[8];
    #pragma unroll
    for (int tau = 0; tau < 8; ++tau) {
        int w = tau >> 1, j = tau & 1;
        int G = 8 * w + (nl & 7) + 32 * ((nl >> 3) + 2 * j);
        #pragma unroll
        for (int kc = 0; kc < 4; ++kc)
            bw1[tau][kc] = load8f_h(w_ih1 + G * 128 + kc * 32 + qd * 8);
        bh1[tau] = load8f_h(w_hh1 + G * 32 + qd * 8);
    }
    h8_t bw2[4], bh2[4];
    #pragma unroll
    for (int tau = 0; tau < 4; ++tau) {
        int a = tau >> 1, b = tau & 1;
        int G = 32 * b + 16 * (nl >> 3) + 8 * a + (nl & 7);
        bw2[tau] = load8f_h(w_ih2 + G * 32 + qd * 8);
        bh2[tau] = (qd < 2) ? load8f_h(w_hh2 + G * 16 + qd * 8) : zero8h();
    }
    h8_t b3c[2];
    #pragma unroll
    for (int tau = 0; tau < 2; ++tau) {
        int G = 16 * tau + 8 * (nl >> 3) + (nl & 7);
        b3c[tau] = (qd < 2) ? load8f_h(w_ih3 + G * 16 + qd * 8)
                 : (qd == 2) ? load8f_h(w_hh3 + G * 8) : zero8h();
    }
    float bs1[2][4], bs2[4], bs3[4];
    #pragma unroll
    for (int d = 0; d < 2; ++d) {
        int U = 16 * d + nl;
        #pragma unroll
        for (int g = 0; g < 4; ++g) bs1[d][g] = b_ih1[32 * g + U] + b_hh1[32 * g + U];
    }
    #pragma unroll
    for (int g = 0; g < 4; ++g) bs2[g] = b_ih2[16 * g + nl] + b_hh2[16 * g + nl];
    {
        int u3 = nl & 7;
        #pragma unroll
        for (int g = 0; g < 4; ++g) bs3[g] = b_ih3[8 * g + u3] + b_hh3[8 * g + u3];
    }

    // zero both parities of all h-state LDS (h[-1], h[-2], h[-3] = 0)
    for (int i = lane; i < 2 * 16 * 40; i += 64) (&h1s[0][0][0])[i] = (_Float16)0.f;
    for (int i = lane; i < 2 * 16 * 24; i += 64) (&h2s[0][0][0])[i] = (_Float16)0.f;
    for (int i = lane; i < 2 * 16 * 8;  i += 64) (&h3s[0][0][0])[i] = (_Float16)0.f;

    float c1[2][4] = {{0.f,0.f,0.f,0.f},{0.f,0.f,0.f,0.f}};
    float c2v[4] = {0.f,0.f,0.f,0.f};
    float c3v[2] = {0.f,0.f};

    const int b0 = blockIdx.x * 16;
    const float* xbase = x + ((size_t)(b0 + nl) * T_LEN) * D_IN + qd * 8;
    f4_t xa[8];
    #pragma unroll
    for (int kc = 0; kc < 4; ++kc) {
        xa[2 * kc]     = *(const f4_t*)(xbase + kc * 32);
        xa[2 * kc + 1] = *(const f4_t*)(xbase + kc * 32 + 4);
    }

    // ---------------- one pipelined iteration ----------------
    auto step = [&](auto d1c, auto d2c, auto d3c, auto pc, int t) {
        constexpr bool DO1 = decltype(d1c)::value;
        constexpr bool DO2 = decltype(d2c)::value;
        constexpr bool DO3 = decltype(d3c)::value;
        constexpr int  P   = decltype(pc)::value;

        if constexpr (DO1) {
            // convert x_t, prefetch x_{t+1} (clamped, branchless)
            h8_t af[4];
            #pragma unroll
            for (int kc = 0; kc < 4; ++kc) af[kc] = cvt8(xa[2 * kc], xa[2 * kc + 1]);
            {
                int tn = (t + 1 < T_LEN) ? (t + 1) : t;
                const float* xn = xbase + (size_t)tn * D_IN;
                #pragma unroll
                for (int kc = 0; kc < 4; ++kc) {
                    xa[2 * kc]     = *(const f4_t*)(xn + kc * 32);
                    xa[2 * kc + 1] = *(const f4_t*)(xn + kc * 32 + 4);
                }
            }

            h8_t a1p = *(const h8_t*)&h1s[1 - P][nl][qd * 8];    // h1[t-1]
            f4_t acc[8];
            #pragma unroll
            for (int tau = 0; tau < 8; ++tau) {
                f4_t a_ = {0.f, 0.f, 0.f, 0.f};
                #pragma unroll
                for (int kc = 0; kc < 4; ++kc)
                    a_ = __builtin_amdgcn_mfma_f32_16x16x32_f16(af[kc], bw1[tau][kc], a_, 0, 0, 0);
                a_ = __builtin_amdgcn_mfma_f32_16x16x32_f16(a1p, bh1[tau], a_, 0, 0, 0);
                acc[tau] = a_;
            }
            #pragma unroll
            for (int d = 0; d < 2; ++d)
            #pragma unroll
            for (int r = 0; r < 4; ++r) {
                float eL = acc[4*d+0][r], oL = acc[4*d+1][r];
                float eH = acc[4*d+2][r], oH = acc[4*d+3][r];
                float exL = __shfl_xor(eL, 8, 64), exH = __shfl_xor(eH, 8, 64);
                float oxL = __shfl_xor(oL, 8, 64), oxH = __shfl_xor(oH, 8, 64);
                float vi = lo8 ? eL  : exH;
                float vf = lo8 ? exL : eH;
                float vg = lo8 ? oL  : oxH;
                float vo = lo8 ? oxL : oH;
                float ig = sig_(vi + bs1[d][0]);
                float fg = sig_(vf + bs1[d][1]);
                float gg = tanh_(vg + bs1[d][2]);
                float og = sig_(vo + bs1[d][3]);
                float c = fg * c1[d][r] + ig * gg; c1[d][r] = c;
                float h = og * tanh_(c);
                h1s[P][4 * qd + r][16 * d + nl] = (_Float16)h;   // h1[t]
            }
        }

        if constexpr (DO2) {
            h8_t a1c = *(const h8_t*)&h1s[1 - P][nl][qd * 8];    // h1[t-1]
            h8_t a2p = zero8h();
            if (qd < 2) a2p = *(const h8_t*)&h2s[P][nl][qd * 8]; // h2[t-2]
            f4_t acc2[4];
            #pragma unroll
            for (int tau = 0; tau < 4; ++tau) {
                f4_t a_ = {0.f, 0.f, 0.f, 0.f};
                a_ = __builtin_amdgcn_mfma_f32_16x16x32_f16(a1c, bw2[tau], a_, 0, 0, 0);
                a_ = __builtin_amdgcn_mfma_f32_16x16x32_f16(a2p, bh2[tau], a_, 0, 0, 0);
                acc2[tau] = a_;
            }
            #pragma unroll
            for (int r = 0; r < 4; ++r) {
                float eL = acc2[0][r], oL = acc2[1][r];
                float eH = acc2[2][r], oH = acc2[3][r];
                float exL = __shfl_xor(eL, 8, 64), exH = __shfl_xor(eH, 8, 64);
                float oxL = __shfl_xor(oL, 8, 64), oxH = __shfl_xor(oH, 8, 64);
                float vi = lo8 ? eL  : exH;
                float vf = lo8 ? exL : eH;
                float vg = lo8 ? oL  : oxH;
                float vo = lo8 ? oxL : oH;
                float ig = sig_(vi + bs2[0]);
                float fg = sig_(vf + bs2[1]);
                float gg = tanh_(vg + bs2[2]);
                float og = sig_(vo + bs2[3]);
                float c = fg * c2v[r] + ig * gg; c2v[r] = c;
                float h = og * tanh_(c);
                h2s[1 - P][4 * qd + r][nl] = (_Float16)h;        // h2[t-1]
            }
        }

        if constexpr (DO3) {
            h8_t a3 = zero8h();
            if (qd < 2)       a3 = *(const h8_t*)&h2s[P][nl][qd * 8];  // h2[t-2]
            else if (qd == 2) a3 = *(const h8_t*)&h3s[1 - P][nl][0];   // h3[t-3]
            f4_t acc3[2];
            #pragma unroll
            for (int tau = 0; tau < 2; ++tau) {
                f4_t a_ = {0.f, 0.f, 0.f, 0.f};
                acc3[tau] = __builtin_amdgcn_mfma_f32_16x16x32_f16(a3, b3c[tau], a_, 0, 0, 0);
            }
            #pragma unroll
            for (int rp = 0; rp < 2; ++rp) {
                float eLo = acc3[0][rp],     oLo = acc3[1][rp];
                float eHi = acc3[0][rp + 2], oHi = acc3[1][rp + 2];
                float exLo = __shfl_xor(eLo, 8, 64), exHi = __shfl_xor(eHi, 8, 64);
                float oxLo = __shfl_xor(oLo, 8, 64), oxHi = __shfl_xor(oHi, 8, 64);
                float vi = lo8 ? eLo  : exHi;
                float vf = lo8 ? exLo : eHi;
                float vg = lo8 ? oLo  : oxHi;
                float vo = lo8 ? oxLo : oHi;
                float ig = sig_(vi + bs3[0]);
                float fg = sig_(vf + bs3[1]);
                float gg = tanh_(vg + bs3[2]);
                float og = sig_(vo + bs3[3]);
                float c = fg * c3v[rp] + ig * gg; c3v[rp] = c;
                float h = og * tanh_(c);
                int m = 4 * qd + rp + (lo8 ? 0 : 2);
                h3s[P][m][nl & 7] = (_Float16)h;                 // h3[t-2]
            }
        }
    };

    using TT = std::integral_constant<bool, true>;
    using FF = std::integral_constant<bool, false>;
    using P0 = std::integral_constant<int, 0>;
    using P1 = std::integral_constant<int, 1>;

    // warm-up
    step(TT{}, FF{}, FF{}, P0{}, 0);
    step(TT{}, TT{}, FF{}, P1{}, 1);
    // main: t = 2..63, parity static via x2 unroll
    for (int tb = 1; tb < 32; ++tb) {
        step(TT{}, TT{}, TT{}, P0{}, 2 * tb);
        step(TT{}, TT{}, TT{}, P1{}, 2 * tb + 1);
    }
    // drain
    step(FF{}, TT{}, TT{}, P0{}, 64);
    step(FF{}, FF{}, TT{}, P1{}, 65);

    // ---------------- FC head: h3[63] is in h3s[1] ----------------
    if (lane < 16) {
        float a = fc_b[0];
        #pragma unroll
        for (int u = 0; u < 8; ++u)
            a += fc_w[u] * (float)h3s[1][lane][u];
        out[b0 + lane] = a;
    }
}

extern "C" void kernel_launch(void* const* d_in, const int* in_sizes, int n_in,
                              void* d_out, int out_size, void* d_ws, size_t ws_size,
                              hipStream_t stream) {
    (void)in_sizes; (void)n_in; (void)out_size; (void)d_ws; (void)ws_size;
    const float* x     = (const float*)d_in[0];
    const float* w_ih1 = (const float*)d_in[1];
    const float* w_hh1 = (const float*)d_in[2];
    const float* b_ih1 = (const float*)d_in[3];
    const float* b_hh1 = (const float*)d_in[4];
    const float* w_ih2 = (const float*)d_in[5];
    const float* w_hh2 = (const float*)d_in[6];
    const float* b_ih2 = (const float*)d_in[7];
    const float* b_hh2 = (const float*)d_in[8];
    const float* w_ih3 = (const float*)d_in[9];
    const float* w_hh3 = (const float*)d_in[10];
    const float* b_ih3 = (const float*)d_in[11];
    const float* b_hh3 = (const float*)d_in[12];
    const float* fc_w  = (const float*)d_in[13];
    const float* fc_b  = (const float*)d_in[14];

    dim3 grid(512), block(64);
    hipLaunchKernelGGL(lstm_one, grid, block, 0, stream,
                       x, w_ih1, w_hh1, b_ih1, b_hh1,
                       w_ih2, w_hh2, b_ih2, b_hh2,
                       w_ih3, w_hh3, b_ih3, b_hh3,
                       fc_w, fc_b, (float*)d_out);
}